// Round 10
// baseline (3291.995 us; speedup 1.0000x reference)
//
#include <hip/hip_runtime.h>
#include <hip/hip_bf16.h>
#include <cmath>

// GateNetwork gate: scores = x[16384,8192] @ W[128,8192]^T + b
//                   probs = softmax(scores); top8; out = (softmax(top8 probs), idx)
// Round 10 = resubmit (R5-R9 all died in GPU acquisition; this code has never
// run). Theory from R1 (the only run ever): indices-only absmax 5.0 > 2.54 ==
// top-8 boundary flip from fp32 sequential-K rounding vs numpy-f64 reference.
// f64 accumulate -> zero flips. R4's container failure attributed to
// unconditional 8 MB d_ws use; now gated:
//   ws >= 8 MB: Wt f64, pure v_fma_f64 from s_load  (~480-560 us predicted)
//   else:       Wt f32 (4 MB, proven in R1), per-use v_cvt_f64_f32 (+50% VALU)
// Both branches produce bit-identical scores (f32 exactly representable in
// f64), so the correctness verdict is branch-independent.
// Contingency: if this RUNS and still fails indices with small absmax, the
// np reference is fp32 BLAS and the strategy pivots to matching numpy's
// summation structure, not adding precision.

#define B_ROWS 16384
#define D_DIM  8192
#define E_DIM  128
#define TOPK   8

#define BK       32
#define ROWS     64
#define XS_PITCH 68   // f32 x-tile: staging writes 4-way, compute reads conflict-free
#define SS_PITCH 129  // f64 scores: row pitch 258 words == 2 mod 32 -> b64 ops conflict-free

// ---------------- Kernel 1: W[E][D] f32 -> Wt[D][E] (f64 or f32) ----------------
template <typename WT>
__global__ __launch_bounds__(256) void transpose_w(const float* __restrict__ W,
                                                   WT* __restrict__ Wt) {
    __shared__ float t[32][33];
    const int kx = blockIdx.x * 32;  // D index base
    const int ey = blockIdx.y * 32;  // E index base
    const int tx = threadIdx.x;      // 0..31
    const int ty = threadIdx.y;      // 0..7
#pragma unroll
    for (int j = 0; j < 32; j += 8)
        t[ty + j][tx] = W[(size_t)(ey + ty + j) * D_DIM + kx + tx];
    __syncthreads();
#pragma unroll
    for (int j = 0; j < 32; j += 8)
        Wt[(size_t)(kx + ty + j) * E_DIM + ey + tx] = (WT)t[tx][ty + j];
}

__device__ __forceinline__ double shfl_xor_d(double v, int m) {
    union { double d; int i[2]; } u;
    u.d = v;
    u.i[0] = __shfl_xor(u.i[0], m);
    u.i[1] = __shfl_xor(u.i[1], m);
    return u.d;
}

// ---------------- Kernel 2: fused GEMM(f64 acc) + softmax + top-k ----------------
template <typename WT>
__global__ __launch_bounds__(512) void gate_kernel(const float* __restrict__ x,
                                                   const WT* __restrict__ Wt,
                                                   const float* __restrict__ bias,
                                                   float* __restrict__ out) {
    __shared__ float  xs[2][BK * XS_PITCH];   // f32 x-tile (k-major), double buffered
    __shared__ double ss[ROWS * SS_PITCH];    // scores [64][128] f64, padded

    const int tid  = threadIdx.x;
    const int lane = tid & 63;
    const int wave = tid >> 6;                                   // 0..7
    const int e0   = __builtin_amdgcn_readfirstlane(wave) * 16;  // wave-uniform col base
    const int row0 = blockIdx.x * ROWS;

    // staging map: thread loads one float4; row = tid>>3, k-quad = (tid&7)*4
    const int srow = tid >> 3;
    const int sk4  = (tid & 7) * 4;
    const float* xg = x + (size_t)(row0 + srow) * D_DIM + sk4;

    double acc[16];
#pragma unroll
    for (int j = 0; j < 16; ++j) acc[j] = 0.0;

    // prologue: stage tile 0
    {
        float4 v = *(const float4*)xg;
        float* dst = &xs[0][0];
        dst[(sk4 + 0) * XS_PITCH + srow] = v.x;
        dst[(sk4 + 1) * XS_PITCH + srow] = v.y;
        dst[(sk4 + 2) * XS_PITCH + srow] = v.z;
        dst[(sk4 + 3) * XS_PITCH + srow] = v.w;
    }
    __syncthreads();

    const int NT = D_DIM / BK;  // 256
    for (int t = 0; t < NT; ++t) {
        const int cur = t & 1;
        // issue next tile's global load early (latency hides under the f64 FMA phase)
        float4 vn;
        if (t + 1 < NT) vn = *(const float4*)(xg + (size_t)(t + 1) * BK);

        const WT* wrow = Wt + (size_t)t * BK * E_DIM + e0;  // wave-uniform -> s_load
        const float* xb = &xs[cur][0];
#pragma unroll
        for (int k = 0; k < BK; ++k) {
            const double xv = (double)xb[k * XS_PITCH + lane];
            const WT* wr = wrow + (size_t)k * E_DIM;
#pragma unroll
            for (int j = 0; j < 16; ++j)
                acc[j] = fma(xv, (double)wr[j], acc[j]);
        }

        if (t + 1 < NT) {
            float* dst = &xs[cur ^ 1][0];
            dst[(sk4 + 0) * XS_PITCH + srow] = vn.x;
            dst[(sk4 + 1) * XS_PITCH + srow] = vn.y;
            dst[(sk4 + 2) * XS_PITCH + srow] = vn.z;
            dst[(sk4 + 3) * XS_PITCH + srow] = vn.w;
        }
        __syncthreads();
    }

    // scores -> LDS (f64)
#pragma unroll
    for (int j = 0; j < 16; ++j)
        ss[lane * SS_PITCH + e0 + j] = acc[j] + (double)bias[e0 + j];
    __syncthreads();

    // epilogue: each wave handles 8 rows, all math in f64
    for (int r = wave * 8; r < wave * 8 + 8; ++r) {
        double s0 = ss[r * SS_PITCH + lane];
        double s1 = ss[r * SS_PITCH + lane + 64];

        // softmax over 128 (2 per lane)
        double m = fmax(s0, s1);
#pragma unroll
        for (int s = 32; s > 0; s >>= 1) m = fmax(m, shfl_xor_d(m, s));
        double ev0 = exp(s0 - m);
        double ev1 = exp(s1 - m);
        double Z = ev0 + ev1;
#pragma unroll
        for (int s = 32; s > 0; s >>= 1) Z += shfl_xor_d(Z, s);
        double p0 = ev0 / Z;
        double p1 = ev1 / Z;
        int i0 = lane, i1 = lane + 64;

        // top-8 by repeated wave argmax (ties -> lower index, matching lax.top_k)
        double topv[TOPK];
        int    topi[TOPK];
#pragma unroll
        for (int it = 0; it < TOPK; ++it) {
            double cv; int ci;
            if (p0 >= p1) { cv = p0; ci = i0; } else { cv = p1; ci = i1; }
#pragma unroll
            for (int s = 32; s > 0; s >>= 1) {
                double ov = shfl_xor_d(cv, s);
                int    oi = __shfl_xor(ci, s);
                if (ov > cv || (ov == cv && oi < ci)) { cv = ov; ci = oi; }
            }
            topv[it] = cv;
            topi[it] = ci;
            if (ci == i0) p0 = -1.0;   // probs >= 0, -1 is a safe -inf
            if (ci == i1) p1 = -1.0;
        }

        // reference renorm: softmax over the top-8 PROBS (topv sorted desc, [0] is max)
        const double m2 = topv[0];
        double es[TOPK], s2 = 0.0;
#pragma unroll
        for (int j = 0; j < TOPK; ++j) { es[j] = exp(topv[j] - m2); s2 += es[j]; }
        const double r2 = 1.0 / s2;

        if (lane < TOPK) {
            const size_t o = (size_t)(row0 + r) * TOPK + lane;
            out[o] = (float)(es[lane] * r2);
            out[(size_t)B_ROWS * TOPK + o] = (float)topi[lane];  // indices as float
        }
    }
}

extern "C" void kernel_launch(void* const* d_in, const int* in_sizes, int n_in,
                              void* d_out, int out_size, void* d_ws, size_t ws_size,
                              hipStream_t stream) {
    const float* x    = (const float*)d_in[0];
    const float* W    = (const float*)d_in[1];
    const float* bias = (const float*)d_in[2];
    float* out = (float*)d_out;

    dim3 tb(32, 8);
    dim3 tg(D_DIM / 32, E_DIM / 32);

    const size_t need_f64 = (size_t)D_DIM * E_DIM * sizeof(double);  // 8 MB
    if (ws_size >= need_f64) {
        double* Wt = (double*)d_ws;
        transpose_w<double><<<tg, tb, 0, stream>>>(W, Wt);
        gate_kernel<double><<<B_ROWS / ROWS, 512, 0, stream>>>(x, Wt, bias, out);
    } else {
        float* Wt = (float*)d_ws;  // 4 MB — footprint proven safe by the R1 run
        transpose_w<float><<<tg, tb, 0, stream>>>(W, Wt);
        gate_kernel<float><<<B_ROWS / ROWS, 512, 0, stream>>>(x, Wt, bias, out);
    }
}

// Round 12
// 1717.635 us; speedup vs baseline: 1.9166x; 1.9166x over previous
//
#include <hip/hip_runtime.h>
#include <hip/hip_bf16.h>
#include <cmath>

// GateNetwork gate: scores = x[16384,8192] @ W[128,8192]^T + b
//                   probs = softmax(scores); top8; out = (softmax(top8 probs), idx)
// Round 12 = resubmit of R11 (acquisition timeout; never ran).
// R10 PASSED (f64-accumulation theory confirmed: indices absmax 5->0)
// but ran 2772us with VALUBusy 18% / occupancy 25%: the inner loop read 16 Wt
// doubles from GLOBAL per k with nothing to hide the latency (1 block/CU).
// Fix: W staged through LDS (f32 global -> cvt once -> f64 LDS, double-buffered,
// coalesced), inner loop reads W via wave-uniform broadcast ds_read. BK 32->16
// and epilogue scores overlay the W-LDS region: LDS 83.5KB -> 40.5KB ->
// 2 blocks/CU (16 waves, ~50% occ) with __launch_bounds__(512,4).
// The k-order of fma ops is UNCHANGED -> bit-identical scores to the passing
// R10 run. W stays f32 in d_ws (4MB, R1-proven footprint); ws-gate deleted.
// Predicted: dur 550-800us, VALUBusy 55-80%, occupancy ~50%.

#define B_ROWS 16384
#define D_DIM  8192
#define E_DIM  128
#define TOPK   8

#define BK       16
#define ROWS     64
#define XS_PITCH 68    // f32 x-tile [k][row]: 2-way banks on read+write (free)
#define SS_PITCH 130   // f64 score chunk [16][130] = 16640 B, overlaid on wlds

// ---------------- Kernel 1: W[E][D] f32 -> Wt[D][E] f32 ----------------
__global__ __launch_bounds__(256) void transpose_w(const float* __restrict__ W,
                                                   float* __restrict__ Wt) {
    __shared__ float t[32][33];
    const int kx = blockIdx.x * 32;  // D index base
    const int ey = blockIdx.y * 32;  // E index base
    const int tx = threadIdx.x;      // 0..31
    const int ty = threadIdx.y;      // 0..7
#pragma unroll
    for (int j = 0; j < 32; j += 8)
        t[ty + j][tx] = W[(size_t)(ey + ty + j) * D_DIM + kx + tx];
    __syncthreads();
#pragma unroll
    for (int j = 0; j < 32; j += 8)
        Wt[(size_t)(kx + ty + j) * E_DIM + ey + tx] = t[tx][ty + j];
}

__device__ __forceinline__ double shfl_xor_d(double v, int m) {
    union { double d; int i[2]; } u;
    u.d = v;
    u.i[0] = __shfl_xor(u.i[0], m);
    u.i[1] = __shfl_xor(u.i[1], m);
    return u.d;
}

// ---------------- Kernel 2: fused GEMM(f64 acc) + softmax + top-k ----------------
__global__ __launch_bounds__(512, 4) void gate_kernel(const float* __restrict__ x,
                                                      const float* __restrict__ Wt,
                                                      const float* __restrict__ bias,
                                                      float* __restrict__ out) {
    __shared__ double wlds[2][BK][E_DIM];     // 32 KB; reused as score chunk in epilogue
    __shared__ float  xs[2][BK * XS_PITCH];   // 8.5 KB, k-major

    const int tid  = threadIdx.x;
    const int lane = tid & 63;
    const int wave = tid >> 6;                                   // 0..7
    const int e0   = __builtin_amdgcn_readfirstlane(wave) * 16;  // wave-uniform col base
    const int row0 = blockIdx.x * ROWS;

    // W staging map: thread -> 4 consecutive f32 of the [16][128] tile
    const int wk = tid >> 5;          // 0..15 (k within tile)
    const int we = (tid & 31) * 4;    // 0,4,...,124 (expert)
    const float* wg = Wt + (size_t)wk * E_DIM + we;
    // x staging map: thread -> 2 consecutive f32 of one row
    const int xrow = tid >> 3;        // 0..63
    const int xk   = (tid & 7) * 2;   // 0,2,...,14
    const float* xg = x + (size_t)(row0 + xrow) * D_DIM + xk;

    double acc[16];
#pragma unroll
    for (int j = 0; j < 16; ++j) acc[j] = 0.0;

    // prologue: stage tile 0
    {
        float4 wv = *(const float4*)wg;
        float2 xv = *(const float2*)xg;
        wlds[0][wk][we + 0] = (double)wv.x;
        wlds[0][wk][we + 1] = (double)wv.y;
        wlds[0][wk][we + 2] = (double)wv.z;
        wlds[0][wk][we + 3] = (double)wv.w;
        xs[0][(xk + 0) * XS_PITCH + xrow] = xv.x;
        xs[0][(xk + 1) * XS_PITCH + xrow] = xv.y;
    }
    __syncthreads();

    const int NT = D_DIM / BK;  // 512
    for (int t = 0; t < NT; ++t) {
        const int cur = t & 1;
        // issue next tile's global loads early (HBM latency hides under ~1100-cyc compute)
        float4 wv;
        float2 xv;
        if (t + 1 < NT) {
            wv = *(const float4*)(wg + (size_t)(t + 1) * BK * E_DIM);
            xv = *(const float2*)(xg + (size_t)(t + 1) * BK);
        }

        const float*  xb = &xs[cur][0];
#pragma unroll
        for (int kk = 0; kk < BK; ++kk) {
            const double xd = (double)xb[kk * XS_PITCH + lane];
            const double* wr = &wlds[cur][kk][e0];   // wave-uniform -> broadcast ds_read
#pragma unroll
            for (int j = 0; j < 16; ++j)
                acc[j] = fma(xd, wr[j], acc[j]);
        }

        if (t + 1 < NT) {
            const int nb = cur ^ 1;
            wlds[nb][wk][we + 0] = (double)wv.x;
            wlds[nb][wk][we + 1] = (double)wv.y;
            wlds[nb][wk][we + 2] = (double)wv.z;
            wlds[nb][wk][we + 3] = (double)wv.w;
            xs[nb][(xk + 0) * XS_PITCH + xrow] = xv.x;
            xs[nb][(xk + 1) * XS_PITCH + xrow] = xv.y;
        }
        __syncthreads();
    }
    // loop ends with a barrier -> all compute done; wlds reusable as score buffer

    double* ss = &wlds[0][0][0];  // [16][SS_PITCH] f64 chunk = 16640 B <= 32 KB

    // epilogue in 4 chunks of 16 rows
    for (int c = 0; c < 4; ++c) {
        if ((lane >> 4) == c) {
            const int lr = lane & 15;
#pragma unroll
            for (int j = 0; j < 16; ++j)
                ss[lr * SS_PITCH + e0 + j] = acc[j] + (double)bias[e0 + j];
        }
        __syncthreads();

#pragma unroll
        for (int q = 0; q < 2; ++q) {
            const int lr = wave * 2 + q;  // 0..15 within chunk
            double s0 = ss[lr * SS_PITCH + lane];
            double s1 = ss[lr * SS_PITCH + lane + 64];

            // softmax over 128 (2 per lane)
            double m = fmax(s0, s1);
#pragma unroll
            for (int s = 32; s > 0; s >>= 1) m = fmax(m, shfl_xor_d(m, s));
            double ev0 = exp(s0 - m);
            double ev1 = exp(s1 - m);
            double Z = ev0 + ev1;
#pragma unroll
            for (int s = 32; s > 0; s >>= 1) Z += shfl_xor_d(Z, s);
            double p0 = ev0 / Z;
            double p1 = ev1 / Z;
            int i0 = lane, i1 = lane + 64;

            // top-8 by repeated wave argmax (ties -> lower index, matching lax.top_k)
            double topv[TOPK];
            int    topi[TOPK];
#pragma unroll
            for (int it = 0; it < TOPK; ++it) {
                double cv; int ci;
                if (p0 >= p1) { cv = p0; ci = i0; } else { cv = p1; ci = i1; }
#pragma unroll
                for (int s = 32; s > 0; s >>= 1) {
                    double ov = shfl_xor_d(cv, s);
                    int    oi = __shfl_xor(ci, s);
                    if (ov > cv || (ov == cv && oi < ci)) { cv = ov; ci = oi; }
                }
                topv[it] = cv;
                topi[it] = ci;
                if (ci == i0) p0 = -1.0;   // probs >= 0, -1 is a safe -inf
                if (ci == i1) p1 = -1.0;
            }

            // reference renorm: softmax over the top-8 PROBS (topv sorted desc)
            const double m2 = topv[0];
            double es[TOPK], s2 = 0.0;
#pragma unroll
            for (int j = 0; j < TOPK; ++j) { es[j] = exp(topv[j] - m2); s2 += es[j]; }
            const double r2 = 1.0 / s2;

            if (lane < TOPK) {
                const int grow = row0 + c * 16 + lr;
                const size_t o = (size_t)grow * TOPK + lane;
                out[o] = (float)(es[lane] * r2);
                out[(size_t)B_ROWS * TOPK + o] = (float)topi[lane];  // indices as float
            }
        }
        __syncthreads();  // before next chunk overwrites ss
    }
}

extern "C" void kernel_launch(void* const* d_in, const int* in_sizes, int n_in,
                              void* d_out, int out_size, void* d_ws, size_t ws_size,
                              hipStream_t stream) {
    const float* x    = (const float*)d_in[0];
    const float* W    = (const float*)d_in[1];
    const float* bias = (const float*)d_in[2];
    float* out = (float*)d_out;
    float* Wt  = (float*)d_ws;  // 8192*128*4 = 4 MB scratch (R1-proven footprint)

    dim3 tb(32, 8);
    dim3 tg(D_DIM / 32, E_DIM / 32);
    transpose_w<<<tg, tb, 0, stream>>>(W, Wt);
    gate_kernel<<<B_ROWS / ROWS, 512, 0, stream>>>(x, Wt, bias, out);
}